// Round 1
// 306.016 us; speedup vs baseline: 1.1244x; 1.1244x over previous
//
#include <hip/hip_runtime.h>

// N=20000, E=640000, D_IN=256, HID1=512 (4 heads x 128), D_OUT=128, R=32.
// fp32 in/out; internal bf16. GEMM commuted past aggregation.
// This rev: CSR build via LDS-privatized counting sort (no global deg/cursor
// atomics), counts packed to 8-bit fields, aggregate1 restructured to
// 2-edges-per-wave-iteration with explicit v_pk_fma_f32, row prefetch in
// both aggregation kernels.

#define D_IN   256
#define HID1   512
#define NHEADS 4
#define DOUT   128
#define NREL   32
#define NEG_SLOPE 0.2f
#define M_PAD  20096   // 157*128 == 314*64
#define NB     128     // counting-sort blocks (E/NB = 5000)

static __device__ __forceinline__ unsigned short f2b(float f) {
  union { float f; unsigned int i; } v; v.f = f;
  unsigned int x = v.i;
  return (unsigned short)((x + 0x7fffu + ((x >> 16) & 1u)) >> 16);
}
static __device__ __forceinline__ float lrelu(float x) {
  return x > 0.f ? x : NEG_SLOPE * x;
}

typedef __attribute__((ext_vector_type(8))) short bf16x8;
typedef __attribute__((ext_vector_type(4))) float f32x4;
typedef __attribute__((ext_vector_type(2))) float f32x2;

// unpack dword (2 bf16) -> f32x2
static __device__ __forceinline__ f32x2 up2(unsigned int u) {
  union { unsigned int i; float f; } lo, hi;
  lo.i = u << 16; hi.i = u & 0xffff0000u;
  f32x2 v; v.x = lo.f; v.y = hi.f; return v;
}
// guaranteed packed fma: a = b*c + a
static __device__ __forceinline__ void pkfma(f32x2& a, f32x2 b, f32x2 c) {
  asm("v_pk_fma_f32 %0, %1, %2, %0" : "+v"(a) : "v"(b), "v"(c));
}
// packed acc: acc[0..3] (f32x2 each) += w * (8 bf16 in uint4)
static __device__ __forceinline__ void accp(f32x2* acc, float w, uint4 r) {
  f32x2 wv = (f32x2)(w);
  pkfma(acc[0], wv, up2(r.x));
  pkfma(acc[1], wv, up2(r.y));
  pkfma(acc[2], wv, up2(r.z));
  pkfma(acc[3], wv, up2(r.w));
}
// 4-head accumulate for aggregate1 (per-lane: 8 ch x 4 heads of one row)
static __device__ __forceinline__ void acc4(f32x2 acc[4][4], float* den,
                                            float4 av, float4 adv, uint4 r) {
  float w0 = __expf(lrelu(av.x + adv.x));
  float w1 = __expf(lrelu(av.y + adv.y));
  float w2 = __expf(lrelu(av.z + adv.z));
  float w3 = __expf(lrelu(av.w + adv.w));
  f32x2 x0 = up2(r.x), x1 = up2(r.y), x2 = up2(r.z), x3 = up2(r.w);
  f32x2 wv;
  wv = (f32x2)(w0);
  pkfma(acc[0][0], wv, x0); pkfma(acc[0][1], wv, x1);
  pkfma(acc[0][2], wv, x2); pkfma(acc[0][3], wv, x3);
  wv = (f32x2)(w1);
  pkfma(acc[1][0], wv, x0); pkfma(acc[1][1], wv, x1);
  pkfma(acc[1][2], wv, x2); pkfma(acc[1][3], wv, x3);
  wv = (f32x2)(w2);
  pkfma(acc[2][0], wv, x0); pkfma(acc[2][1], wv, x1);
  pkfma(acc[2][2], wv, x2); pkfma(acc[2][3], wv, x3);
  wv = (f32x2)(w3);
  pkfma(acc[3][0], wv, x0); pkfma(acc[3][1], wv, x1);
  pkfma(acc[3][2], wv, x2); pkfma(acc[3][3], wv, x3);
  den[0] += w0; den[1] += w1; den[2] += w2; den[3] += w3;
}

// ---- hist + prep: LDS dst-histogram per block, 8-bit packed (src,rel)
//      counts, weight casts, u/vs/vd precompute --------------------------
__global__ __launch_bounds__(256) void hist_prep_kernel(
    const int* __restrict__ src, const int* __restrict__ dst,
    const int* __restrict__ et, unsigned int* __restrict__ counts8,
    int* __restrict__ gtable, int E, int n, int cb,
    const float* __restrict__ W1, const float* __restrict__ W2,
    unsigned short* __restrict__ W1T, unsigned short* __restrict__ W2T,
    const float* __restrict__ att_s1, const float* __restrict__ att_d1,
    float* __restrict__ us4, float* __restrict__ ud4,
    const float* __restrict__ att_s2, const float* __restrict__ att_d2,
    float* __restrict__ vs, float* __restrict__ vd) {
  int b = blockIdx.x;
  int t = threadIdx.x;
  if (b < NB) {
    extern __shared__ int hist[];  // n ints (80 KB)
    for (int i = t; i < n; i += 256) hist[i] = 0;
    __syncthreads();
    int per = (E + NB - 1) / NB;
    int e0 = b * per;
    int e1 = min(e0 + per, E);
    for (int e = e0 + t; e < e1; e += 256) {
      atomicAdd(&hist[dst[e]], 1);                    // LDS atomic
      int s = src[e], r = et[e];
      atomicAdd(&counts8[(size_t)s * 8 + (r >> 2)], 1u << (8 * (r & 3)));
    }
    __syncthreads();
    for (int i = t; i < n; i += 256) gtable[(size_t)b * n + i] = hist[i];
  } else if (b < NB + cb) {
    int idx = (b - NB) * 256 + t;
    if (idx < D_IN * HID1) {
      int r = idx / HID1, c = idx % HID1;
      W1T[(size_t)c * D_IN + r] = f2b(W1[idx]);
    } else {
      int k = idx - D_IN * HID1;
      if (k < HID1 * DOUT) {
        int r = k / DOUT, c = k % DOUT;
        W2T[(size_t)c * HID1 + r] = f2b(W2[k]);
      }
    }
  } else if (b == NB + cb) {
    int k = t;  // 0..255
    float us[4] = {0.f, 0.f, 0.f, 0.f}, ud[4] = {0.f, 0.f, 0.f, 0.f};
    for (int h = 0; h < 4; ++h)
      for (int c = 0; c < 128; ++c) {
        float wv = W1[(size_t)k * HID1 + h * 128 + c];
        us[h] += wv * att_s1[h * 128 + c];
        ud[h] += wv * att_d1[h * 128 + c];
      }
    ((float4*)us4)[k] = make_float4(us[0], us[1], us[2], us[3]);
    ((float4*)ud4)[k] = make_float4(ud[0], ud[1], ud[2], ud[3]);
  } else {
#pragma unroll
    for (int rr = 0; rr < 2; ++rr) {
      int r = t * 2 + rr;  // 0..511
      float ss = 0.f, dd = 0.f;
      for (int c = 0; c < DOUT; ++c) {
        float wv = W2[(size_t)r * DOUT + c];
        ss += wv * att_s2[c];
        dd += wv * att_d2[c];
      }
      vs[r] = ss; vd[r] = dd;
    }
  }
}

// ---- deg[d] = sum_b gtable[b][d] ------------------------------------------
__global__ void colsum_kernel(const int* __restrict__ gtable,
                              int* __restrict__ deg, int n) {
  int d = blockIdx.x * 256 + threadIdx.x;
  if (d >= n) return;
  int s = 0;
#pragma unroll 8
  for (int b = 0; b < NB; ++b) s += gtable[(size_t)b * n + d];
  deg[d] = s;
}

// ---- scan -----------------------------------------------------------------
__global__ void scan_local(const int* __restrict__ in, int* __restrict__ out,
                           int* __restrict__ bsum, int n) {
  __shared__ int wsum[4];
  int t = threadIdx.x;
  int base = blockIdx.x * 1024 + t * 4;
  int v0 = (base + 0 < n) ? in[base + 0] : 0;
  int v1 = (base + 1 < n) ? in[base + 1] : 0;
  int v2 = (base + 2 < n) ? in[base + 2] : 0;
  int v3 = (base + 3 < n) ? in[base + 3] : 0;
  int s = v0 + v1 + v2 + v3;
  int lane = t & 63, w = t >> 6;
  int sc = s;
  for (int off = 1; off < 64; off <<= 1) {
    int u = __shfl_up(sc, off);
    if (lane >= off) sc += u;
  }
  if (lane == 63) wsum[w] = sc;
  __syncthreads();
  int woff = 0;
  for (int i = 0; i < w; ++i) woff += wsum[i];
  int excl = woff + sc - s;
  if (base + 0 < n) out[base + 0] = excl;
  if (base + 1 < n) out[base + 1] = excl + v0;
  if (base + 2 < n) out[base + 2] = excl + v0 + v1;
  if (base + 3 < n) out[base + 3] = excl + v0 + v1 + v2;
  if (t == 255) bsum[blockIdx.x] = woff + sc;
}

__global__ void scan_blocks(int* __restrict__ bsum, int nb,
                            int* __restrict__ offsets, int n) {
  int t = threadIdx.x;  // 64
  int v = (t < nb) ? bsum[t] : 0;
  int sc = v;
  for (int off = 1; off < 64; off <<= 1) {
    int u = __shfl_up(sc, off);
    if (t >= off) sc += u;
  }
  if (t < nb) bsum[t] = sc - v;
  if (t == nb - 1) offsets[n] = v;
}

// ---- gtable[b][d] -> absolute base positions ------------------------------
__global__ void rebase_kernel(int* __restrict__ gtable,
                              const int* __restrict__ offsets,
                              const int* __restrict__ bsum, int n) {
  int d = blockIdx.x * 256 + threadIdx.x;
  if (d >= n) return;
  int run = offsets[d] + bsum[d >> 10];
  for (int b = 0; b < NB; ++b) {
    size_t idx = (size_t)b * n + d;
    int v = gtable[idx];
    gtable[idx] = run;
    run += v;
  }
}

// ---- scatter via LDS fetch-add (no global atomics) ------------------------
__global__ __launch_bounds__(256) void scatter2_kernel(
    const int* __restrict__ src, const int* __restrict__ dst,
    const int* __restrict__ gtable, int* __restrict__ csr_src, int E, int n) {
  extern __shared__ int cur[];  // n ints
  int b = blockIdx.x;
  int t = threadIdx.x;
  for (int i = t; i < n; i += 256) cur[i] = gtable[(size_t)b * n + i];
  __syncthreads();
  int per = (E + NB - 1) / NB;
  int e0 = b * per;
  int e1 = min(e0 + per, E);
  for (int e = e0 + t; e < e1; e += 256) {
    int pos = atomicAdd(&cur[dst[e]], 1);  // LDS fetch-add
    csr_src[pos] = src[e];
  }
}

// ---- x_mod + fused logits as1/ad1 (8-bit packed counts) -------------------
__global__ __launch_bounds__(256) void xmod_kernel(
    const float* __restrict__ x, const unsigned int* __restrict__ counts8,
    const float* __restrict__ rel, const float* __restrict__ us4,
    const float* __restrict__ ud4, unsigned short* __restrict__ x_modb,
    float* __restrict__ as1, float* __restrict__ ad1, int n_nodes) {
  int wv = threadIdx.x >> 6;
  int node = blockIdx.x * 4 + wv;
  if (node >= n_nodes) return;
  int l = threadIdx.x & 63;
  int r5 = l & 31;
  unsigned int cw = counts8[(size_t)node * 8 + (r5 >> 2)];
  int cnt_l = (int)((cw >> (8 * (r5 & 3))) & 0xffu);
  const float4* x4 = (const float4*)x;
  const float4* rel4 = (const float4*)rel;
  float4 v = x4[(size_t)node * 64 + l];
#pragma unroll
  for (int r = 0; r < NREL; ++r) {
    int c = __shfl(cnt_l, r);  // wave-uniform
    if (c) {
      float4 rv = rel4[r * 64 + l];
      float fc = (float)c;
      v.x += fc * rv.x; v.y += fc * rv.y; v.z += fc * rv.z; v.w += fc * rv.w;
    }
  }
  ushort4 o;
  o.x = f2b(v.x); o.y = f2b(v.y); o.z = f2b(v.z); o.w = f2b(v.w);
  *(ushort4*)(x_modb + (size_t)node * D_IN + l * 4) = o;
  const float4* usv = (const float4*)us4;
  const float4* udv = (const float4*)ud4;
  float vv[4] = {v.x, v.y, v.z, v.w};
  float sh[4] = {0.f, 0.f, 0.f, 0.f}, dh[4] = {0.f, 0.f, 0.f, 0.f};
#pragma unroll
  for (int i = 0; i < 4; ++i) {
    float4 uu = usv[l * 4 + i];
    float4 dd = udv[l * 4 + i];
    sh[0] += vv[i] * uu.x; sh[1] += vv[i] * uu.y; sh[2] += vv[i] * uu.z; sh[3] += vv[i] * uu.w;
    dh[0] += vv[i] * dd.x; dh[1] += vv[i] * dd.y; dh[2] += vv[i] * dd.z; dh[3] += vv[i] * dd.w;
  }
  for (int off = 32; off; off >>= 1) {
#pragma unroll
    for (int h = 0; h < 4; ++h) {
      sh[h] += __shfl_xor(sh[h], off);
      dh[h] += __shfl_xor(dh[h], off);
    }
  }
  if (l == 0) {
    ((float4*)as1)[node] = make_float4(sh[0], sh[1], sh[2], sh[3]);
    ((float4*)ad1)[node] = make_float4(dh[0], dh[1], dh[2], dh[3]);
  }
}

// ---- layer-1 aggregate: one wave/node, 2 edges per wave-iteration ---------
// half = lane>>5 owns one edge; 32 lanes x uint4 cover the full 512B row;
// per lane: 8 channels x 4 heads. Cross-half shfl_xor(32) reduce at end.
__global__ __launch_bounds__(256) void aggregate1_kernel(
    const unsigned short* __restrict__ x_modb,
    const float* __restrict__ as1, const float* __restrict__ ad1,
    const int* __restrict__ offsets, const int* __restrict__ bsum,
    const int* __restrict__ csr_src,
    unsigned short* __restrict__ agg_xb, int n_nodes) {
  int node = blockIdx.x * 4 + (threadIdx.x >> 6);
  if (node >= n_nodes) return;
  int lane = threadIdx.x & 63;
  int half = lane >> 5, l32 = lane & 31;
  int lo = offsets[node] + bsum[node >> 10];
  int hi = offsets[node + 1] + bsum[(node + 1) >> 10];
  float4 adv = ((const float4*)ad1)[node];
  const uint4* xv = (const uint4*)x_modb;  // 32 uint4 per 512B row
  const float4* as1v = (const float4*)as1;

  f32x2 acc[4][4];  // [head][dword]
#pragma unroll
  for (int h = 0; h < 4; ++h)
#pragma unroll
    for (int k = 0; k < 4; ++k) acc[h][k] = (f32x2)(0.f);
  float den[4] = {0.f, 0.f, 0.f, 0.f};

  int j = lo + half;
  int s = (j < hi) ? csr_src[j] : node;
  float4 av = as1v[(unsigned)s];
  uint4 r = xv[(unsigned)((s << 5) | l32)];
  while (j < hi) {
    int jn = j + 2;
    int sn = (jn < hi) ? csr_src[jn] : node;
    float4 avn = as1v[(unsigned)sn];
    uint4 rn = xv[(unsigned)((sn << 5) | l32)];  // 1-ahead prefetch
    acc4(acc, den, av, adv, r);
    j = jn; s = sn; av = avn; r = rn;
  }
  if (half == 0) {  // self loop (one half only)
    float4 asv = as1v[(unsigned)node];
    uint4 rs = xv[(unsigned)((node << 5) | l32)];
    acc4(acc, den, asv, adv, rs);
  }
  // cross-half reduction
#pragma unroll
  for (int h = 0; h < 4; ++h) {
#pragma unroll
    for (int k = 0; k < 4; ++k) {
      acc[h][k].x += __shfl_xor(acc[h][k].x, 32);
      acc[h][k].y += __shfl_xor(acc[h][k].y, 32);
    }
    den[h] += __shfl_xor(den[h], 32);
  }
  if (half == 0) {
#pragma unroll
    for (int h = 0; h < 4; ++h) {
      float inv = 1.f / (den[h] + 1e-16f);
      uint4 o;
      o.x = (unsigned)f2b(acc[h][0].x * inv) | ((unsigned)f2b(acc[h][0].y * inv) << 16);
      o.y = (unsigned)f2b(acc[h][1].x * inv) | ((unsigned)f2b(acc[h][1].y * inv) << 16);
      o.z = (unsigned)f2b(acc[h][2].x * inv) | ((unsigned)f2b(acc[h][2].y * inv) << 16);
      o.w = (unsigned)f2b(acc[h][3].x * inv) | ((unsigned)f2b(acc[h][3].y * inv) << 16);
      *(uint4*)(agg_xb + ((size_t)h * M_PAD + node) * D_IN + l32 * 8) = o;
    }
  }
}

// ---- bf16 MFMA GEMM. MODE 1: per-head A slice + bias/ELU/as2-ad2 epilogue -
template <int BM, int MODE>
__global__ __launch_bounds__(256) void mfma_gemm(
    const unsigned short* __restrict__ A, const unsigned short* __restrict__ BT,
    unsigned short* __restrict__ C, int M, int N, int K,
    const float* __restrict__ bias, const float* __restrict__ vs,
    const float* __restrict__ vd, float* __restrict__ as2, float* __restrict__ ad2) {
  constexpr int MFR = BM / 32;
  __shared__ __align__(16) unsigned short Asl[BM * 32];
  __shared__ __align__(16) unsigned short Bsl[128 * 32];
  int tid = threadIdx.x;
  int m0 = blockIdx.y * BM, n0 = blockIdx.x * 128;
  int lane = tid & 63, wv = tid >> 6;
  int wm = wv & 1, wn = wv >> 1;
  int l16 = lane & 15, quad = lane >> 4;
  int lr = lane >> 2, lseg = lane & 3;
  if (MODE == 1) A += (size_t)blockIdx.x * M_PAD * K;  // head slice

  f32x4 acc[MFR][4];
#pragma unroll
  for (int i = 0; i < MFR; ++i)
#pragma unroll
    for (int j = 0; j < 4; ++j) acc[i][j] = (f32x4)(0.f);

  for (int k0 = 0; k0 < K; k0 += 32) {
#pragma unroll
    for (int c = wv; c < BM / 16; c += 4) {
      int gr = m0 + c * 16 + lr; gr = gr < M ? gr : M - 1;
      __builtin_amdgcn_global_load_lds(
          (const __attribute__((address_space(1))) void*)(A + (size_t)gr * K + k0 + lseg * 8),
          (__attribute__((address_space(3))) void*)(&Asl[c * 512]), 16, 0, 0);
    }
#pragma unroll
    for (int c = wv; c < 8; c += 4) {
      int gr = n0 + c * 16 + lr;
      __builtin_amdgcn_global_load_lds(
          (const __attribute__((address_space(1))) void*)(BT + (size_t)gr * K + k0 + lseg * 8),
          (__attribute__((address_space(3))) void*)(&Bsl[c * 512]), 16, 0, 0);
    }
    __syncthreads();
    bf16x8 af[MFR], bfr[4];
#pragma unroll
    for (int mf = 0; mf < MFR; ++mf)
      af[mf] = *(const bf16x8*)(&Asl[(wm * (BM / 2) + mf * 16 + l16) * 32 + quad * 8]);
#pragma unroll
    for (int nf = 0; nf < 4; ++nf)
      bfr[nf] = *(const bf16x8*)(&Bsl[(wn * 64 + nf * 16 + l16) * 32 + quad * 8]);
#pragma unroll
    for (int mf = 0; mf < MFR; ++mf)
#pragma unroll
      for (int nf = 0; nf < 4; ++nf)
        acc[mf][nf] = __builtin_amdgcn_mfma_f32_16x16x32_bf16(af[mf], bfr[nf], acc[mf][nf], 0, 0, 0);
    __syncthreads();
  }
  if (MODE == 0) {
#pragma unroll
    for (int mf = 0; mf < MFR; ++mf)
#pragma unroll
      for (int nf = 0; nf < 4; ++nf)
#pragma unroll
        for (int r = 0; r < 4; ++r) {
          int row = m0 + wm * (BM / 2) + mf * 16 + quad * 4 + r;
          int col = n0 + wn * 64 + nf * 16 + l16;
          C[(size_t)row * N + col] = f2b(acc[mf][nf][r]);
        }
  } else {
#pragma unroll
    for (int mf = 0; mf < MFR; ++mf)
#pragma unroll
      for (int r = 0; r < 4; ++r) {
        int row = m0 + wm * (BM / 2) + mf * 16 + quad * 4 + r;
        float sd = 0.f, dd = 0.f;
#pragma unroll
        for (int nf = 0; nf < 4; ++nf) {
          int col = n0 + wn * 64 + nf * 16 + l16;
          float cv = acc[mf][nf][r] + bias[col];
          cv = cv > 0.f ? cv : expm1f(cv);  // ELU
          C[(size_t)row * N + col] = f2b(cv);
          sd += cv * vs[col];
          dd += cv * vd[col];
        }
#pragma unroll
        for (int off = 1; off < 16; off <<= 1) {
          sd += __shfl_xor(sd, off);
          dd += __shfl_xor(dd, off);
        }
        if (l16 == 0 && row < M) {
          atomicAdd(&as2[row], sd);
          atomicAdd(&ad2[row], dd);
        }
      }
  }
}

// ---- layer-2 aggregate: one wave/node, 4 groups, packed acc, row prefetch -
__global__ __launch_bounds__(256) void aggregate2_kernel(
    const unsigned short* __restrict__ t2b,
    const float* __restrict__ as2, const float* __restrict__ ad2,
    const int* __restrict__ offsets, const int* __restrict__ bsum,
    const int* __restrict__ csr_src,
    const float* __restrict__ bias, float* __restrict__ out, int n_nodes) {
  int node = blockIdx.x * 4 + (threadIdx.x >> 6);
  if (node >= n_nodes) return;
  int lane = threadIdx.x & 63;
  int g = lane >> 4, l16 = lane & 15;
  int lo = offsets[node] + bsum[node >> 10];
  int hi = offsets[node + 1] + bsum[(node + 1) >> 10];
  float ad = ad2[node];

  const uint4* t2v = (const uint4*)t2b;
  f32x2 acc[4];
#pragma unroll
  for (int k = 0; k < 4; ++k) acc[k] = (f32x2)(0.f);
  float denom = 0.f;
  int nit = (hi - lo + 3) >> 2;
  int j = lo + g;
  bool valid = j < hi;
  int s = valid ? csr_src[j] : node;
  float asv = as2[s];
  uint4 tv = t2v[(unsigned)((s << 4) | l16)];
  for (int i = 0; i < nit; ++i) {
    int jn = j + 4;
    bool vn = jn < hi;
    int sn = vn ? csr_src[jn] : node;
    float asv_n = as2[sn];
    uint4 tvn = t2v[(unsigned)((sn << 4) | l16)];  // 1-ahead prefetch
    float w = valid ? __expf(lrelu(asv + ad)) : 0.f;
    accp(acc, w, tv);
    denom += w;
    j = jn; valid = vn; s = sn; asv = asv_n; tv = tvn;
  }
  if (g == 0) {  // self loop
    uint4 tv2 = t2v[(unsigned)((node << 4) | l16)];
    float w = __expf(lrelu(as2[node] + ad));
    accp(acc, w, tv2);
    denom += w;
  }
#pragma unroll
  for (int k = 0; k < 4; ++k) {
    acc[k].x += __shfl_xor(acc[k].x, 16); acc[k].y += __shfl_xor(acc[k].y, 16);
    acc[k].x += __shfl_xor(acc[k].x, 32); acc[k].y += __shfl_xor(acc[k].y, 32);
  }
  denom += __shfl_xor(denom, 16);
  denom += __shfl_xor(denom, 32);
  if (g == 0) {
    float inv = 1.f / (denom + 1e-16f);
    float4 o0, o1;
    o0.x = acc[0].x * inv + bias[l16 * 8 + 0];
    o0.y = acc[0].y * inv + bias[l16 * 8 + 1];
    o0.z = acc[1].x * inv + bias[l16 * 8 + 2];
    o0.w = acc[1].y * inv + bias[l16 * 8 + 3];
    o1.x = acc[2].x * inv + bias[l16 * 8 + 4];
    o1.y = acc[2].y * inv + bias[l16 * 8 + 5];
    o1.z = acc[3].x * inv + bias[l16 * 8 + 6];
    o1.w = acc[3].y * inv + bias[l16 * 8 + 7];
    *(float4*)(out + (size_t)node * DOUT + l16 * 8) = o0;
    *(float4*)(out + (size_t)node * DOUT + l16 * 8 + 4) = o1;
  }
}

extern "C" void kernel_launch(void* const* d_in, const int* in_sizes, int n_in,
                              void* d_out, int out_size, void* d_ws, size_t ws_size,
                              hipStream_t stream) {
  const float* x     = (const float*)d_in[0];
  const int* ei      = (const int*)d_in[1];
  const int* etype   = (const int*)d_in[2];
  const float* rel   = (const float*)d_in[3];
  const float* W1    = (const float*)d_in[4];
  const float* at_s1 = (const float*)d_in[5];
  const float* at_d1 = (const float*)d_in[6];
  const float* b1    = (const float*)d_in[7];
  const float* W2    = (const float*)d_in[8];
  const float* at_s2 = (const float*)d_in[9];
  const float* at_d2 = (const float*)d_in[10];
  const float* b2v   = (const float*)d_in[11];
  float* out         = (float*)d_out;

  const int N = in_sizes[0] / D_IN;  // 20000
  const int E = in_sizes[2];         // 640000
  const int* srcv = ei;
  const int* dstv = ei + E;

  char* p = (char*)d_ws;
  auto carve = [&](size_t bytes) -> char* {
    char* r = p; p += (bytes + 255) & ~(size_t)255; return r;
  };
  // zeroed region (packed counts + as2/ad2 atomic accumulators)
  unsigned int* counts8 = (unsigned int*)carve((size_t)N * 8 * 4);  // 640 KB
  float* as2     = (float*)carve((size_t)N * 4);
  float* ad2     = (float*)carve((size_t)N * 4);
  size_t zero_bytes = (size_t)(p - (char*)counts8);
  // plain scratch
  int*   deg     = (int*)carve((size_t)N * 4);
  int*   offsets = (int*)carve(((size_t)N + 1) * 4);
  int*   bsum    = (int*)carve(64 * 4);
  float* as1     = (float*)carve((size_t)N * NHEADS * 4);
  float* ad1     = (float*)carve((size_t)N * NHEADS * 4);
  float* vs      = (float*)carve((size_t)HID1 * 4);
  float* vd      = (float*)carve((size_t)HID1 * 4);
  float* us4     = (float*)carve((size_t)D_IN * 4 * 4);
  float* ud4     = (float*)carve((size_t)D_IN * 4 * 4);
  int*   csr_src = (int*)carve((size_t)E * 4);
  unsigned short* W1T    = (unsigned short*)carve((size_t)HID1 * D_IN * 2);
  unsigned short* W2T    = (unsigned short*)carve((size_t)DOUT * HID1 * 2);
  unsigned short* x_modb = (unsigned short*)carve((size_t)N * D_IN * 2);
  unsigned short* agg_xb = (unsigned short*)carve((size_t)NHEADS * M_PAD * D_IN * 2);
  unsigned short* h2b    = (unsigned short*)carve((size_t)M_PAD * HID1 * 2);
  unsigned short* t2b    = (unsigned short*)carve((size_t)M_PAD * DOUT * 2);
  // gtable (NB x N ints = 10.24 MB) aliases h2b (20.6 MB): last gtable read
  // (scatter2) precedes first h2b write (gemm1) in stream order.
  int* gtable = (int*)h2b;

  hipMemsetAsync(counts8, 0, zero_bytes, stream);

  int cb = (D_IN * HID1 + HID1 * DOUT + 255) / 256;  // 768
  int nb = (N + 1023) / 1024;                        // 20
  int ldsb = N * 4;                                  // 80 KB dynamic LDS
  hist_prep_kernel<<<NB + cb + 2, 256, ldsb, stream>>>(
      srcv, dstv, etype, counts8, gtable, E, N, cb,
      W1, W2, W1T, W2T, at_s1, at_d1, us4, ud4, at_s2, at_d2, vs, vd);
  colsum_kernel<<<(N + 255) / 256, 256, 0, stream>>>(gtable, deg, N);
  scan_local<<<nb, 256, 0, stream>>>(deg, offsets, bsum, N);
  scan_blocks<<<1, 64, 0, stream>>>(bsum, nb, offsets, N);
  rebase_kernel<<<(N + 255) / 256, 256, 0, stream>>>(gtable, offsets, bsum, N);
  scatter2_kernel<<<NB, 256, ldsb, stream>>>(srcv, dstv, gtable, csr_src, E, N);
  xmod_kernel<<<(N + 3) / 4, 256, 0, stream>>>(x, counts8, rel, us4, ud4, x_modb, as1, ad1, N);
  aggregate1_kernel<<<(N + 3) / 4, 256, 0, stream>>>(x_modb, as1, ad1, offsets, bsum,
                                                     csr_src, agg_xb, N);
  mfma_gemm<128, 1><<<dim3(NHEADS, M_PAD / 128), 256, 0, stream>>>(
      agg_xb, W1T, h2b, N, HID1, D_IN, b1, vs, vd, as2, ad2);
  mfma_gemm<64, 0><<<dim3(DOUT / 128, M_PAD / 64), 256, 0, stream>>>(
      h2b, W2T, t2b, N, DOUT, HID1, nullptr, nullptr, nullptr, nullptr, nullptr);
  aggregate2_kernel<<<(N + 3) / 4, 256, 0, stream>>>(
      t2b, as2, ad2, offsets, bsum, csr_src, b2v, out, N);
}